// Round 2
// baseline (6095.892 us; speedup 1.0000x reference)
//
#include <hip/hip_runtime.h>
#include <hip/hip_bf16.h>

#define V 50257
#define D 128
#define NN 3
#define KK 3
#define TT 256
#define NSTEPS 5
#define EPSF 1e-10f

// ws layout (float offsets)
#define WS_M  0          // [9][128][128]  M = B B^T
#define WS_BT 147456     // [9][128][128]  BT[d][e] = B[e][d]
#define WS_U  294912     // [256][9][128]  normalized expr vectors per step
#define WS_Z  589824     // [256] softmax denominators

__device__ __forceinline__ float wred(float v) {
  v += __shfl_xor(v, 1);  v += __shfl_xor(v, 2);  v += __shfl_xor(v, 4);
  v += __shfl_xor(v, 8);  v += __shfl_xor(v, 16); v += __shfl_xor(v, 32);
  return v;
}

// ---------------- init: M = B B^T (fp32), BT = B^T ----------------
__global__ void foam_init(const float* __restrict__ Bg, float* __restrict__ ws)
{
  const int kn = blockIdx.x;     // 0..8
  const int part = blockIdx.y;   // 0..3
  const int tid = threadIdx.x;   // 256
  __shared__ float Bs[128][129];
  for (int idx = tid; idx < 16384; idx += 256) {
    int e = idx >> 7, d = idx & 127;
    Bs[e][d] = Bg[(size_t)kn * 16384 + idx];
  }
  __syncthreads();
  float* Mw = ws + WS_M  + (size_t)kn * 16384;
  float* Tw = ws + WS_BT + (size_t)kn * 16384;
  const int base = part * 4096;
  for (int idx = base + tid; idx < base + 4096; idx += 256) {
    int e = idx >> 7, f = idx & 127;
    float acc = 0.f;
    #pragma unroll 4
    for (int d = 0; d < 128; ++d) acc = fmaf(Bs[e][d], Bs[f][d], acc);
    Mw[idx] = acc;
    // idx interpreted as (d=e, col=f): BT[d][col] = B[col][d]
    Tw[idx] = Bs[f][e];
  }
}

// ---------------- per-k equilibrate over all 256 steps ----------------
__device__ __forceinline__ void matvec3(
  const float (&A0)[32], const float (&A1)[32], const float (&A2)[32],
  const float* v0, const float* v1, const float* v2,
  int f0, float (*parts)[3][132], int r, int c)
{
  float a0 = 0.f, a1 = 0.f, a2 = 0.f;
  #pragma unroll
  for (int j = 0; j < 32; j += 4) {
    const float4 x0 = *reinterpret_cast<const float4*>(v0 + f0 + j);
    const float4 x1 = *reinterpret_cast<const float4*>(v1 + f0 + j);
    const float4 x2 = *reinterpret_cast<const float4*>(v2 + f0 + j);
    a0 = fmaf(A0[j], x0.x, fmaf(A0[j+1], x0.y, fmaf(A0[j+2], x0.z, fmaf(A0[j+3], x0.w, a0))));
    a1 = fmaf(A1[j], x1.x, fmaf(A1[j+1], x1.y, fmaf(A1[j+2], x1.z, fmaf(A1[j+3], x1.w, a1))));
    a2 = fmaf(A2[j], x2.x, fmaf(A2[j+1], x2.y, fmaf(A2[j+2], x2.z, fmaf(A2[j+3], x2.w, a2))));
  }
  parts[c][0][r] = a0; parts[c][1][r] = a1; parts[c][2][r] = a2;
}

__global__ __launch_bounds__(512, 2) void foam_equil(
  const int* __restrict__ tokens, const float* __restrict__ E,
  const float* __restrict__ tension, const float* __restrict__ temperature,
  const float* __restrict__ target_sim, const float* __restrict__ step_size,
  const float* __restrict__ anchor_logit, const float* __restrict__ mdbp,
  const float* __restrict__ sensp, float* __restrict__ ws)
{
  const int k    = blockIdx.x;
  const int tid  = threadIdx.x;
  const int lane = tid & 63;
  const int wv   = tid >> 6;   // 0..7
  const int r    = tid & 127;
  const int c    = tid >> 7;   // 0..3
  const int f0   = c * 32;

  const float* Mw = ws + WS_M  + (size_t)(3 * k) * 16384;
  const float* Tw = ws + WS_BT + (size_t)(3 * k) * 16384;
  float* Uw = ws + WS_U;

  float M0[32], M1[32], M2[32], T0[32], T1[32], T2[32];
  {
    const float* m0 = Mw + r * 128 + f0;
    const float* t0 = Tw + r * 128 + f0;
    #pragma unroll
    for (int j = 0; j < 32; ++j) {
      M0[j] = m0[j];         M1[j] = m0[j + 16384]; M2[j] = m0[j + 32768];
      T0[j] = t0[j];         T1[j] = t0[j + 16384]; T2[j] = t0[j + 32768];
    }
  }

  const float temp = fmaxf(fabsf(temperature[k]), 0.01f);
  const float tgt  = target_sim[k];
  const float stp  = fminf(fmaxf(fabsf(step_size[k]), 0.001f), 0.5f);
  const float aw   = 1.f / (1.f + expf(-anchor_logit[k]));
  const float mdbv = mdbp[0];
  const float sensv = fabsf(sensp[0]);

  __shared__ float inter_s[3][3];
  __shared__ __align__(16) float xs[128], mm[128], xwm[128];
  __shared__ __align__(16) float expr_s[3][128], ffv[3][128], fsv[3][128];
  __shared__ float parts[4][3][132];
  __shared__ float dotb[16];

  if (tid < 9) {
    int n = tid / 3, m = tid % 3;
    float a0 = -tension[(k * 3 + n) * 3 + 0] / temp;
    float a1 = -tension[(k * 3 + n) * 3 + 1] / temp;
    float a2 = -tension[(k * 3 + n) * 3 + 2] / temp;
    float mx = fmaxf(a0, fmaxf(a1, a2));
    float s  = expf(a0 - mx) + expf(a1 - mx) + expf(a2 - mx);
    float av = (m == 0) ? a0 : ((m == 1) ? a1 : a2);
    inter_s[n][m] = expf(av - mx) / s;
  }
  if (tid < 128) mm[tid] = 0.f;
  __syncthreads();

  for (int t = 0; t < TT; ++t) {
    const int tok = tokens[t];
    // load x, zero force-sum
    if (tid < 128) xs[tid] = E[(size_t)tok * 128 + tid];
    {
      int q = tid - 128;
      if (q >= 0) fsv[q >> 7][q & 127] = 0.f;
    }
    __syncthreads();
    // 3 dots: |x|^2, |mm|^2, mm.x
    if (wv < 3) {
      float p = 0.f;
      for (int f = lane; f < 128; f += 64) {
        float a = (wv == 0) ? xs[f] * xs[f] : ((wv == 1) ? mm[f] * mm[f] : mm[f] * xs[f]);
        p += a;
      }
      p = wred(p);
      if (lane == 0) dotb[wv] = p;
    }
    __syncthreads();
    const float xn   = sqrtf(dotb[0]) + EPSF;
    const float mmn  = sqrtf(dotb[1]) + EPSF;
    const float cosv = dotb[2] / (xn * mmn);
    const float nov  = (mmn > 1e-8f) ? (1.f - cosv) : 1.f;
    const float decay = 1.f / (1.f + expf(-(mdbv - sensv * nov)));
    if (tid < 128) xwm[tid] = xs[tid] + decay * mm[tid];
    __syncthreads();
    // expr0 = M x_wm ; also |x_wm|^2
    matvec3(M0, M1, M2, xwm, xwm, xwm, f0, parts, r, c);
    if (wv == 0) {
      float p = 0.f;
      for (int f = lane; f < 128; f += 64) p += xwm[f] * xwm[f];
      p = wred(p);
      if (lane == 0) dotb[3] = p;
    }
    __syncthreads();
    const float anorm = sqrtf(dotb[3]) + EPSF;
    if (tid < 384) {
      int n = tid >> 7, d = tid & 127;
      expr_s[n][d] = parts[0][n][d] + parts[1][n][d] + parts[2][n][d] + parts[3][n][d];
    }
    __syncthreads();

    for (int it = 0; it < NSTEPS; ++it) {
      // 15 dots
      for (int dd = wv; dd < 15; dd += 8) {
        float p = 0.f;
        for (int f = lane; f < 128; f += 64) {
          float val;
          if (dd < 3) { float a = expr_s[dd][f]; val = a * a; }
          else if (dd < 6) { int pi = dd - 3; int a = pi >> 1, b = pi ? 2 : 1;
                             val = expr_s[a][f] * expr_s[b][f]; }
          else if (dd < 9) { val = expr_s[dd - 6][f] * xwm[f]; }
          else if (dd < 12) { int pi = dd - 9; int a = pi >> 1, b = pi ? 2 : 1;
                              float dv = expr_s[a][f] - expr_s[b][f]; val = dv * dv; }
          else { float dv = expr_s[dd - 12][f] - xwm[f]; val = dv * dv; }
          p += val;
        }
        p = wred(p);
        if (lane == 0) dotb[dd] = p;
      }
      __syncthreads();
      // forces
      if (tid < 384) {
        int n = tid >> 7, d = tid & 127;
        float en = sqrtf(dotb[n]) + EPSF;
        float force = 0.f;
        #pragma unroll
        for (int m = 0; m < 3; ++m) {
          if (m == n) continue;
          int pi = n + m - 1;                  // (0,1)->0 (0,2)->1 (1,2)->2
          float em = sqrtf(dotb[m]) + EPSF;
          float cs = dotb[3 + pi] / (en * em);
          float fmag = (cs - tgt) * inter_s[n][m];
          float dn = sqrtf(dotb[9 + pi]) + EPSF;
          force += fmag * (expr_s[n][d] - expr_s[m][d]) / dn;
        }
        float asim = dotb[6 + n] / (en * anorm);
        float afm = (asim - tgt) * aw;
        float adn = sqrtf(dotb[12 + n]) + EPSF;
        force += afm * (expr_s[n][d] - xwm[d]) / adn;
        ffv[n][d] = force;
        fsv[n][d] += force;
      }
      __syncthreads();
      matvec3(M0, M1, M2, ffv[0], ffv[1], ffv[2], f0, parts, r, c);
      __syncthreads();
      if (tid < 384) {
        int n = tid >> 7, d = tid & 127;
        expr_s[n][d] += stp * (parts[0][n][d] + parts[1][n][d] + parts[2][n][d] + parts[3][n][d]);
      }
      __syncthreads();
    }

    // finalize: w = x_wm + stp*fs ; final norms
    if (tid < 384) {
      int n = tid >> 7, d = tid & 127;
      ffv[n][d] = xwm[d] + stp * fsv[n][d];
    }
    if (wv < 3) {
      float p = 0.f;
      for (int f = lane; f < 128; f += 64) { float a = expr_s[wv][f]; p += a * a; }
      p = wred(p);
      if (lane == 0) dotb[wv] = p;
    }
    __syncthreads();
    // state = BT * w (3 matvecs); write U
    matvec3(T0, T1, T2, ffv[0], ffv[1], ffv[2], f0, parts, r, c);
    if (tid < 384) {
      int n = tid >> 7, d = tid & 127;
      float en = sqrtf(dotb[n]) + EPSF;
      Uw[(size_t)t * 1152 + k * 384 + n * 128 + d] = expr_s[n][d] / en;
    }
    __syncthreads();
    if (tid < 128) {
      float sm = 0.f;
      #pragma unroll
      for (int cc = 0; cc < 4; ++cc)
        sm += parts[cc][0][tid] + parts[cc][1][tid] + parts[cc][2][tid];
      sm *= (1.f / 3.f);
      mm[tid] = decay * mm[tid] + (1.f - decay) * sm;
    }
    __syncthreads();
  }
}

// ---------------- spectral entropy per step (9x9 Gram + Jacobi) ----------------
__global__ void foam_entropy(const float* __restrict__ U, float* __restrict__ out)
{
  const int t = blockIdx.x;
  const int lane = threadIdx.x; // 64
  __shared__ float Us9[9][132];
  __shared__ float G[9][12];
  for (int idx = lane; idx < 1152; idx += 64)
    Us9[idx >> 7][idx & 127] = U[(size_t)t * 1152 + idx];
  __syncthreads();
  if (lane < 45) {
    int i = 0, rem = lane;
    while (rem >= 9 - i) { rem -= 9 - i; ++i; }
    int j = i + rem;
    float p = 0.f;
    for (int f = 0; f < 128; ++f) p = fmaf(Us9[i][f], Us9[j][f], p);
    p *= (1.f / 9.f);
    G[i][j] = p; G[j][i] = p;
  }
  __syncthreads();
  for (int sw = 0; sw < 8; ++sw) {
    for (int p = 0; p < 8; ++p) {
      for (int q = p + 1; q < 9; ++q) {
        float app = G[p][p], aqq = G[q][q], apq = G[p][q];
        bool doit = fabsf(apq) > 1e-20f;
        float c_ = 1.f, s_ = 0.f;
        if (doit) {
          float tau = (aqq - app) / (2.f * apq);
          float tsg = (tau >= 0.f) ? 1.f : -1.f;
          float tt = tsg / (fabsf(tau) + sqrtf(1.f + tau * tau));
          c_ = 1.f / sqrtf(1.f + tt * tt);
          s_ = tt * c_;
        }
        __syncthreads();
        if (doit) {
          if (lane < 9 && lane != p && lane != q) {
            float gp = G[p][lane], gq = G[q][lane];
            float np_ = c_ * gp - s_ * gq;
            float nq_ = s_ * gp + c_ * gq;
            G[p][lane] = np_; G[lane][p] = np_;
            G[q][lane] = nq_; G[lane][q] = nq_;
          }
          if (lane == 0) {
            float npp = c_ * c_ * app - 2.f * c_ * s_ * apq + s_ * s_ * aqq;
            float nqq = s_ * s_ * app + 2.f * c_ * s_ * apq + c_ * c_ * aqq;
            G[p][p] = npp; G[q][q] = nqq; G[p][q] = 0.f; G[q][p] = 0.f;
          }
        }
        __syncthreads();
      }
    }
  }
  if (lane == 0) {
    float tot = 119.f * 1e-12f;
    float lam[9];
    #pragma unroll
    for (int i = 0; i < 9; ++i) { lam[i] = fmaxf(G[i][i], 1e-12f); tot += lam[i]; }
    float S = 0.f;
    #pragma unroll
    for (int i = 0; i < 9; ++i) {
      float le = lam[i] / tot;
      S -= le * fmaxf(logf(le), -100.f);
    }
    float lz = 1e-12f / tot;
    S -= 119.f * (lz * fmaxf(logf(lz), -100.f));
    out[(size_t)TT * V + t] = S;
  }
}

// ---------------- logits: l[t,v] = (1/9) sum_i (E[v].u_i(t))^2 ----------------
__global__ __launch_bounds__(256, 2) void foam_logits(
  const float* __restrict__ E, const float* __restrict__ U, float* __restrict__ out)
{
  const int tid = threadIdx.x;
  const int v = blockIdx.x * 256 + tid;
  const bool valid = v < V;
  const int t0 = blockIdx.y * 128;
  float Er[128];
  {
    const float* erow = E + (size_t)(valid ? v : 0) * 128;
    #pragma unroll
    for (int j = 0; j < 128; j += 4) {
      float4 x = *reinterpret_cast<const float4*>(erow + j);
      Er[j] = x.x; Er[j + 1] = x.y; Er[j + 2] = x.z; Er[j + 3] = x.w;
    }
  }
  __shared__ __align__(16) float Us[1152];
  for (int t = t0; t < t0 + 128; ++t) {
    __syncthreads();
    for (int u2 = tid; u2 < 1152; u2 += 256) Us[u2] = U[(size_t)t * 1152 + u2];
    __syncthreads();
    float l = 0.f;
    for (int i = 0; i < 9; ++i) {
      float p = 0.f;
      #pragma unroll
      for (int j = 0; j < 128; j += 4) {
        const float4 uu = *reinterpret_cast<const float4*>(&Us[i * 128 + j]);
        p = fmaf(Er[j], uu.x, fmaf(Er[j + 1], uu.y, fmaf(Er[j + 2], uu.z, fmaf(Er[j + 3], uu.w, p))));
      }
      l = fmaf(p, p, l);
    }
    if (valid) out[(size_t)t * V + v] = l * (1.f / 9.f);
  }
}

// ---------------- softmax denom + H, F ----------------
__global__ __launch_bounds__(1024) void foam_zh(float* __restrict__ out, float* __restrict__ ws)
{
  const int t = blockIdx.x;
  const int tid = threadIdx.x;
  const float* lg = out + (size_t)t * V;
  float z = 0.f, w = 0.f;
  for (int v = tid; v < V; v += 1024) {
    float l = lg[v];
    float e = expf(l);
    z += e; w = fmaf(l, e, w);
  }
  z = wred(z); w = wred(w);
  __shared__ float zb[16], wb[16];
  if ((tid & 63) == 0) { zb[tid >> 6] = z; wb[tid >> 6] = w; }
  __syncthreads();
  if (tid == 0) {
    float Z = 0.f, W = 0.f;
    #pragma unroll
    for (int i = 0; i < 16; ++i) { Z += zb[i]; W += wb[i]; }
    ws[WS_Z + t] = Z;
    float H = logf(Z) - W / Z;
    out[(size_t)TT * V + TT + t] = H;
    out[(size_t)TT * V + 2 * TT + t] = H - out[(size_t)TT * V + t];
  }
}

// ---------------- probs in-place ----------------
__global__ __launch_bounds__(256) void foam_probs(float* __restrict__ out, const float* __restrict__ ws)
{
  const int t = blockIdx.y;
  const int v = blockIdx.x * 256 + threadIdx.x;
  if (v < V) {
    const float zi = 1.f / ws[WS_Z + t];
    float* p = out + (size_t)t * V;
    p[v] = expf(p[v]) * zi;
  }
}

extern "C" void kernel_launch(void* const* d_in, const int* in_sizes, int n_in,
                              void* d_out, int out_size, void* d_ws, size_t ws_size,
                              hipStream_t stream) {
  (void)in_sizes; (void)n_in; (void)out_size; (void)ws_size;
  const int*   tokens      = (const int*)d_in[0];
  const float* E           = (const float*)d_in[1];
  const float* bases       = (const float*)d_in[2];
  const float* tension     = (const float*)d_in[3];
  const float* temperature = (const float*)d_in[4];
  const float* target      = (const float*)d_in[5];
  const float* stepsz      = (const float*)d_in[6];
  const float* alogit      = (const float*)d_in[7];
  const float* mdb         = (const float*)d_in[8];
  const float* sens        = (const float*)d_in[9];
  float* out = (float*)d_out;
  float* ws  = (float*)d_ws;

  foam_init<<<dim3(9, 4), 256, 0, stream>>>(bases, ws);
  foam_equil<<<3, 512, 0, stream>>>(tokens, E, tension, temperature, target,
                                    stepsz, alogit, mdb, sens, ws);
  foam_entropy<<<256, 64, 0, stream>>>(ws + WS_U, out);
  foam_logits<<<dim3(197, 2), 256, 0, stream>>>(E, ws + WS_U, out);
  foam_zh<<<256, 1024, 0, stream>>>(out, ws);
  foam_probs<<<dim3(197, 256), 256, 0, stream>>>(out, ws);
}

// Round 4
// 5710.670 us; speedup vs baseline: 1.0675x; 1.0675x over previous
//
#include <hip/hip_runtime.h>
#include <hip/hip_bf16.h>

#define V 50257
#define D 128
#define NN 3
#define KK 3
#define TT 256
#define NSTEPS 5
#define EPSF 1e-10f

// ws layout (float offsets)
#define WS_M  0          // [9][128][128]  M = B B^T
#define WS_BT 147456     // [9][128][128]  BT[d][e] = B[e][d]
#define WS_U  294912     // [256][9][128]  normalized expr vectors per step
#define WS_Z  589824     // [256] softmax denominators

__device__ __forceinline__ float wred(float v) {
  v += __shfl_xor(v, 1);  v += __shfl_xor(v, 2);  v += __shfl_xor(v, 4);
  v += __shfl_xor(v, 8);  v += __shfl_xor(v, 16); v += __shfl_xor(v, 32);
  return v;
}

// ---------------- init: M = B B^T (fp32), BT = B^T ----------------
__global__ void foam_init(const float* __restrict__ Bg, float* __restrict__ ws)
{
  const int kn = blockIdx.x;     // 0..8
  const int part = blockIdx.y;   // 0..3
  const int tid = threadIdx.x;   // 256
  __shared__ float Bs[128][129];
  for (int idx = tid; idx < 16384; idx += 256) {
    int e = idx >> 7, d = idx & 127;
    Bs[e][d] = Bg[(size_t)kn * 16384 + idx];
  }
  __syncthreads();
  float* Mw = ws + WS_M  + (size_t)kn * 16384;
  float* Tw = ws + WS_BT + (size_t)kn * 16384;
  const int base = part * 4096;
  for (int idx = base + tid; idx < base + 4096; idx += 256) {
    int e = idx >> 7, f = idx & 127;
    float acc = 0.f;
    #pragma unroll 4
    for (int d = 0; d < 128; ++d) acc = fmaf(Bs[e][d], Bs[f][d], acc);
    Mw[idx] = acc;
    Tw[idx] = Bs[f][e];   // BT[d=e][col=f] = B[col][d]
  }
}

// ---------------- per-k equilibrate over all 256 steps ----------------
// 8 waves. wave w owns d-slice [16w,16w+16); lane = fg*16+dl holds
// Mreg[n][j] = M[n][16w+dl][32fg+j]. Wave 0 runs the serial scalar chain
// (dots via in-register butterflies); all waves do the wide matvecs.
// 2 barriers per inner iteration.
__global__ __attribute__((amdgpu_flat_work_group_size(512,512), amdgpu_waves_per_eu(2,2)))
void foam_equil(
  const int* __restrict__ tokens, const float* __restrict__ E,
  const float* __restrict__ tension, const float* __restrict__ temperature,
  const float* __restrict__ target_sim, const float* __restrict__ step_size,
  const float* __restrict__ anchor_logit, const float* __restrict__ mdbp,
  const float* __restrict__ sensp, float* __restrict__ ws)
{
  const int k    = blockIdx.x;
  const int tid  = threadIdx.x;
  const int lane = tid & 63;
  const int wv   = tid >> 6;        // 0..7
  const int fg   = (lane >> 4) & 3; // 0..3
  const int dl   = lane & 15;
  const int down = wv * 16 + dl;    // owned output row d
  const int f0   = fg * 32;         // owned f-range start

  const float* Mw = ws + WS_M  + (size_t)(3 * k) * 16384;
  const float* Tw = ws + WS_BT + (size_t)(3 * k) * 16384;
  float* Uw = ws + WS_U;

  float Mreg[3][32];
  #pragma unroll
  for (int n = 0; n < 3; ++n) {
    const float* src = Mw + n * 16384 + down * 128 + f0;
    #pragma unroll
    for (int j = 0; j < 32; ++j) Mreg[n][j] = src[j];
  }

  const float temp  = fmaxf(fabsf(temperature[k]), 0.01f);
  const float tgt   = target_sim[k];
  const float stp   = fminf(fmaxf(fabsf(step_size[k]), 0.001f), 0.5f);
  const float aw    = 1.f / (1.f + expf(-anchor_logit[k]));
  const float mdbv  = mdbp[0];
  const float sensv = fabsf(sensp[0]);

  // interaction softmax (used by wave 0 only, cheap to compute everywhere)
  float inter[3][3];
  #pragma unroll
  for (int n = 0; n < 3; ++n) {
    float a0 = -tension[(k * 3 + n) * 3 + 0] / temp;
    float a1 = -tension[(k * 3 + n) * 3 + 1] / temp;
    float a2 = -tension[(k * 3 + n) * 3 + 2] / temp;
    float mx = fmaxf(a0, fmaxf(a1, a2));
    float s  = expf(a0 - mx) + expf(a1 - mx) + expf(a2 - mx);
    inter[n][0] = expf(a0 - mx) / s;
    inter[n][1] = expf(a1 - mx) / s;
    inter[n][2] = expf(a2 - mx) / s;
  }

  __shared__ __align__(16) float exprL[3][128];
  __shared__ __align__(16) float fLb[3][128];
  __shared__ __align__(16) float xwmL[128];
  __shared__ __align__(16) float mmL[128];
  __shared__ float scal[2];

  if (tid < 128) mmL[tid] = 0.f;
  __syncthreads();

  for (int t = 0; t < TT; ++t) {
    float xwA = 0.f, xwB = 0.f, gxx = 0.f, anorm = 0.f, decay = 0.f;
    float fsA[3], fsB[3];

    // ---- prologue (wave 0 serial chain) ----
    if (wv == 0) {
      const int tok = tokens[t];
      float xA = E[(size_t)tok * 128 + lane];
      float xB = E[(size_t)tok * 128 + 64 + lane];
      float mA = mmL[lane], mB = mmL[lane + 64];
      float pxx = xA * xA + xB * xB;
      float pmm = mA * mA + mB * mB;
      float pmx = mA * xA + mB * xB;
      pxx = wred(pxx); pmm = wred(pmm); pmx = wred(pmx);
      float xn   = sqrtf(pxx) + EPSF;
      float mmn  = sqrtf(pmm) + EPSF;
      float cosv = pmx / (xn * mmn);
      float nov  = (mmn > 1e-8f) ? (1.f - cosv) : 1.f;
      decay = 1.f / (1.f + expf(-(mdbv - sensv * nov)));
      xwA = xA + decay * mA;
      xwB = xB + decay * mB;
      gxx = pxx + 2.f * decay * pmx + decay * decay * pmm;
      anorm = sqrtf(gxx) + EPSF;
      xwmL[lane] = xwA; xwmL[lane + 64] = xwB;
      if (lane == 0) scal[0] = decay;
      fsA[0] = fsA[1] = fsA[2] = 0.f;
      fsB[0] = fsB[1] = fsB[2] = 0.f;
    }
    __syncthreads();                       // P1

    // ---- expr0 = M * xwm (all waves; slice outputs) ----
    {
      float xf[32];
      const float4* xp = reinterpret_cast<const float4*>(&xwmL[f0]);
      #pragma unroll
      for (int jj = 0; jj < 8; ++jj) {
        float4 x = xp[jj];
        xf[4*jj] = x.x; xf[4*jj+1] = x.y; xf[4*jj+2] = x.z; xf[4*jj+3] = x.w;
      }
      float mv[3];
      #pragma unroll
      for (int n = 0; n < 3; ++n) {
        float a = 0.f;
        #pragma unroll
        for (int j = 0; j < 32; ++j) a = fmaf(Mreg[n][j], xf[j], a);
        a += __shfl_xor(a, 16); a += __shfl_xor(a, 32);
        mv[n] = a;
      }
      if (fg == 0) {
        exprL[0][down] = mv[0]; exprL[1][down] = mv[1]; exprL[2][down] = mv[2];
      }
    }
    __syncthreads();                       // P2

    // ---- 5 equilibration iterations ----
    #pragma unroll 1
    for (int it = 0; it < NSTEPS; ++it) {
      if (wv == 0) {
        float eA[3], eB[3];
        #pragma unroll
        for (int n = 0; n < 3; ++n) { eA[n] = exprL[n][lane]; eB[n] = exprL[n][lane + 64]; }
        // Gram partials: 00,01,02,11,12,22,0x,1x,2x
        float g[9];
        g[0] = eA[0]*eA[0] + eB[0]*eB[0];
        g[1] = eA[0]*eA[1] + eB[0]*eB[1];
        g[2] = eA[0]*eA[2] + eB[0]*eB[2];
        g[3] = eA[1]*eA[1] + eB[1]*eB[1];
        g[4] = eA[1]*eA[2] + eB[1]*eB[2];
        g[5] = eA[2]*eA[2] + eB[2]*eB[2];
        g[6] = eA[0]*xwA + eB[0]*xwB;
        g[7] = eA[1]*xwA + eB[1]*xwB;
        g[8] = eA[2]*xwA + eB[2]*xwB;
        #pragma unroll
        for (int q = 0; q < 9; ++q) {
          float vq = g[q];
          vq += __shfl_xor(vq, 1);  vq += __shfl_xor(vq, 2);  vq += __shfl_xor(vq, 4);
          vq += __shfl_xor(vq, 8);  vq += __shfl_xor(vq, 16); vq += __shfl_xor(vq, 32);
          g[q] = vq;
        }
        float e0n = sqrtf(g[0]) + EPSF;
        float e1n = sqrtf(g[3]) + EPSF;
        float e2n = sqrtf(g[5]) + EPSF;
        float cq01 = g[1] / (e0n * e1n) - tgt;
        float cq02 = g[2] / (e0n * e2n) - tgt;
        float cq12 = g[4] / (e1n * e2n) - tgt;
        float rd01 = 1.f / (sqrtf(fmaxf(g[0] + g[3] - 2.f * g[1], 0.f)) + EPSF);
        float rd02 = 1.f / (sqrtf(fmaxf(g[0] + g[5] - 2.f * g[2], 0.f)) + EPSF);
        float rd12 = 1.f / (sqrtf(fmaxf(g[3] + g[5] - 2.f * g[4], 0.f)) + EPSF);
        float w01 = cq01 * inter[0][1] * rd01, w10 = cq01 * inter[1][0] * rd01;
        float w02 = cq02 * inter[0][2] * rd02, w20 = cq02 * inter[2][0] * rd02;
        float w12 = cq12 * inter[1][2] * rd12, w21 = cq12 * inter[2][1] * rd12;
        float v0 = (g[6] / (e0n * anorm) - tgt) * aw
                 / (sqrtf(fmaxf(g[0] + gxx - 2.f * g[6], 0.f)) + EPSF);
        float v1 = (g[7] / (e1n * anorm) - tgt) * aw
                 / (sqrtf(fmaxf(g[3] + gxx - 2.f * g[7], 0.f)) + EPSF);
        float v2 = (g[8] / (e2n * anorm) - tgt) * aw
                 / (sqrtf(fmaxf(g[5] + gxx - 2.f * g[8], 0.f)) + EPSF);
        float fA0 = w01*(eA[0]-eA[1]) + w02*(eA[0]-eA[2]) + v0*(eA[0]-xwA);
        float fA1 = w10*(eA[1]-eA[0]) + w12*(eA[1]-eA[2]) + v1*(eA[1]-xwA);
        float fA2 = w20*(eA[2]-eA[0]) + w21*(eA[2]-eA[1]) + v2*(eA[2]-xwA);
        float fB0 = w01*(eB[0]-eB[1]) + w02*(eB[0]-eB[2]) + v0*(eB[0]-xwB);
        float fB1 = w10*(eB[1]-eB[0]) + w12*(eB[1]-eB[2]) + v1*(eB[1]-xwB);
        float fB2 = w20*(eB[2]-eB[0]) + w21*(eB[2]-eB[1]) + v2*(eB[2]-xwB);
        fsA[0] += fA0; fsA[1] += fA1; fsA[2] += fA2;
        fsB[0] += fB0; fsB[1] += fB1; fsB[2] += fB2;
        fLb[0][lane] = fA0; fLb[0][lane + 64] = fB0;
        fLb[1][lane] = fA1; fLb[1][lane + 64] = fB1;
        fLb[2][lane] = fA2; fLb[2][lane + 64] = fB2;
      }
      __syncthreads();                     // barrier 1

      // matvec: expr += stp * M * f   (all waves)
      float mv[3];
      #pragma unroll
      for (int n = 0; n < 3; ++n) {
        const float4* fp = reinterpret_cast<const float4*>(&fLb[n][f0]);
        float a = 0.f;
        #pragma unroll
        for (int jj = 0; jj < 8; ++jj) {
          float4 x = fp[jj];
          a = fmaf(Mreg[n][4*jj],   x.x, a);
          a = fmaf(Mreg[n][4*jj+1], x.y, a);
          a = fmaf(Mreg[n][4*jj+2], x.z, a);
          a = fmaf(Mreg[n][4*jj+3], x.w, a);
        }
        a += __shfl_xor(a, 16); a += __shfl_xor(a, 32);
        mv[n] = a;
      }
      if (fg == 0) {
        exprL[0][down] += stp * mv[0];
        exprL[1][down] += stp * mv[1];
        exprL[2][down] += stp * mv[2];
      }
      __syncthreads();                     // barrier 2
    }

    // ---- epilogue: U write + s-vector (wave 0) ----
    if (wv == 0) {
      float eA[3], eB[3];
      #pragma unroll
      for (int n = 0; n < 3; ++n) { eA[n] = exprL[n][lane]; eB[n] = exprL[n][lane + 64]; }
      float s0 = eA[0]*eA[0] + eB[0]*eB[0];
      float s1 = eA[1]*eA[1] + eB[1]*eB[1];
      float s2 = eA[2]*eA[2] + eB[2]*eB[2];
      s0 = wred(s0); s1 = wred(s1); s2 = wred(s2);
      float r0 = 1.f / (sqrtf(s0) + EPSF);
      float r1 = 1.f / (sqrtf(s1) + EPSF);
      float r2 = 1.f / (sqrtf(s2) + EPSF);
      float* ub = Uw + (size_t)t * 1152 + k * 384;
      ub[0 * 128 + lane] = eA[0] * r0;  ub[0 * 128 + lane + 64] = eB[0] * r0;
      ub[1 * 128 + lane] = eA[1] * r1;  ub[1 * 128 + lane + 64] = eB[1] * r1;
      ub[2 * 128 + lane] = eA[2] * r2;  ub[2 * 128 + lane + 64] = eB[2] * r2;
      fLb[0][lane] = xwA + stp * fsA[0];  fLb[0][lane + 64] = xwB + stp * fsB[0];
      fLb[1][lane] = xwA + stp * fsA[1];  fLb[1][lane + 64] = xwB + stp * fsB[1];
      fLb[2][lane] = xwA + stp * fsA[2];  fLb[2][lane + 64] = xwB + stp * fsB[2];
    }
    __syncthreads();                       // E1

    // ---- mm update: mm = decay*mm + (1-decay)/3 * sum_n BT_n * s_n ----
    {
      float a = 0.f;
      #pragma unroll
      for (int n = 0; n < 3; ++n) {
        const float4* tp = reinterpret_cast<const float4*>(Tw + n * 16384 + down * 128 + f0);
        const float4* sp = reinterpret_cast<const float4*>(&fLb[n][f0]);
        #pragma unroll
        for (int jj = 0; jj < 8; ++jj) {
          float4 tv = tp[jj];
          float4 sv = sp[jj];
          a = fmaf(tv.x, sv.x, a); a = fmaf(tv.y, sv.y, a);
          a = fmaf(tv.z, sv.z, a); a = fmaf(tv.w, sv.w, a);
        }
      }
      a += __shfl_xor(a, 16); a += __shfl_xor(a, 32);
      if (fg == 0) {
        float dec = scal[0];
        mmL[down] = dec * mmL[down] + (1.f - dec) * (a * (1.f / 3.f));
      }
    }
    __syncthreads();                       // E2
  }
}

// ---------------- spectral entropy per step (9x9 Gram + Jacobi) ----------------
__global__ void foam_entropy(const float* __restrict__ U, float* __restrict__ out)
{
  const int t = blockIdx.x;
  const int lane = threadIdx.x; // 64
  __shared__ float Us9[9][132];
  __shared__ float G[9][12];
  for (int idx = lane; idx < 1152; idx += 64)
    Us9[idx >> 7][idx & 127] = U[(size_t)t * 1152 + idx];
  __syncthreads();
  if (lane < 45) {
    int i = 0, rem = lane;
    while (rem >= 9 - i) { rem -= 9 - i; ++i; }
    int j = i + rem;
    float p = 0.f;
    for (int f = 0; f < 128; ++f) p = fmaf(Us9[i][f], Us9[j][f], p);
    p *= (1.f / 9.f);
    G[i][j] = p; G[j][i] = p;
  }
  __syncthreads();
  for (int sw = 0; sw < 8; ++sw) {
    for (int p = 0; p < 8; ++p) {
      for (int q = p + 1; q < 9; ++q) {
        float app = G[p][p], aqq = G[q][q], apq = G[p][q];
        bool doit = fabsf(apq) > 1e-20f;
        float c_ = 1.f, s_ = 0.f;
        if (doit) {
          float tau = (aqq - app) / (2.f * apq);
          float tsg = (tau >= 0.f) ? 1.f : -1.f;
          float tt = tsg / (fabsf(tau) + sqrtf(1.f + tau * tau));
          c_ = 1.f / sqrtf(1.f + tt * tt);
          s_ = tt * c_;
        }
        __syncthreads();
        if (doit) {
          if (lane < 9 && lane != p && lane != q) {
            float gp = G[p][lane], gq = G[q][lane];
            float np_ = c_ * gp - s_ * gq;
            float nq_ = s_ * gp + c_ * gq;
            G[p][lane] = np_; G[lane][p] = np_;
            G[q][lane] = nq_; G[lane][q] = nq_;
          }
          if (lane == 0) {
            float npp = c_ * c_ * app - 2.f * c_ * s_ * apq + s_ * s_ * aqq;
            float nqq = s_ * s_ * app + 2.f * c_ * s_ * apq + c_ * c_ * aqq;
            G[p][p] = npp; G[q][q] = nqq; G[p][q] = 0.f; G[q][p] = 0.f;
          }
        }
        __syncthreads();
      }
    }
  }
  if (lane == 0) {
    float tot = 119.f * 1e-12f;
    float lam[9];
    #pragma unroll
    for (int i = 0; i < 9; ++i) { lam[i] = fmaxf(G[i][i], 1e-12f); tot += lam[i]; }
    float S = 0.f;
    #pragma unroll
    for (int i = 0; i < 9; ++i) {
      float le = lam[i] / tot;
      S -= le * fmaxf(logf(le), -100.f);
    }
    float lz = 1e-12f / tot;
    S -= 119.f * (lz * fmaxf(logf(lz), -100.f));
    out[(size_t)TT * V + t] = S;
  }
}

// ---------------- logits: l[t,v] = (1/9) sum_i (E[v].u_i(t))^2 ----------------
__global__ __launch_bounds__(256, 2) void foam_logits(
  const float* __restrict__ E, const float* __restrict__ U, float* __restrict__ out)
{
  const int tid = threadIdx.x;
  const int v = blockIdx.x * 256 + tid;
  const bool valid = v < V;
  const int t0 = blockIdx.y * 32;
  float Er[128];
  {
    const float* erow = E + (size_t)(valid ? v : 0) * 128;
    #pragma unroll
    for (int j = 0; j < 128; j += 4) {
      float4 x = *reinterpret_cast<const float4*>(erow + j);
      Er[j] = x.x; Er[j + 1] = x.y; Er[j + 2] = x.z; Er[j + 3] = x.w;
    }
  }
  __shared__ __align__(16) float Us[1152];
  for (int t = t0; t < t0 + 32; ++t) {
    __syncthreads();
    for (int u2 = tid; u2 < 1152; u2 += 256) Us[u2] = U[(size_t)t * 1152 + u2];
    __syncthreads();
    float l = 0.f;
    for (int i = 0; i < 9; ++i) {
      float p = 0.f;
      #pragma unroll
      for (int j = 0; j < 128; j += 4) {
        const float4 uu = *reinterpret_cast<const float4*>(&Us[i * 128 + j]);
        p = fmaf(Er[j], uu.x, fmaf(Er[j + 1], uu.y, fmaf(Er[j + 2], uu.z, fmaf(Er[j + 3], uu.w, p))));
      }
      l = fmaf(p, p, l);
    }
    if (valid) out[(size_t)t * V + v] = l * (1.f / 9.f);
  }
}

// ---------------- softmax denom + H, F ----------------
__global__ __launch_bounds__(1024) void foam_zh(float* __restrict__ out, float* __restrict__ ws)
{
  const int t = blockIdx.x;
  const int tid = threadIdx.x;
  const float* lg = out + (size_t)t * V;
  float z = 0.f, w = 0.f;
  for (int v = tid; v < V; v += 1024) {
    float l = lg[v];
    float e = expf(l);
    z += e; w = fmaf(l, e, w);
  }
  z = wred(z); w = wred(w);
  __shared__ float zb[16], wb[16];
  if ((tid & 63) == 0) { zb[tid >> 6] = z; wb[tid >> 6] = w; }
  __syncthreads();
  if (tid == 0) {
    float Z = 0.f, W = 0.f;
    #pragma unroll
    for (int i = 0; i < 16; ++i) { Z += zb[i]; W += wb[i]; }
    ws[WS_Z + t] = Z;
    float H = logf(Z) - W / Z;
    out[(size_t)TT * V + TT + t] = H;
    out[(size_t)TT * V + 2 * TT + t] = H - out[(size_t)TT * V + t];
  }
}

// ---------------- probs in-place ----------------
__global__ __launch_bounds__(256) void foam_probs(float* __restrict__ out, const float* __restrict__ ws)
{
  const int t = blockIdx.y;
  const int v = blockIdx.x * 256 + threadIdx.x;
  if (v < V) {
    const float zi = 1.f / ws[WS_Z + t];
    float* p = out + (size_t)t * V;
    p[v] = expf(p[v]) * zi;
  }
}

extern "C" void kernel_launch(void* const* d_in, const int* in_sizes, int n_in,
                              void* d_out, int out_size, void* d_ws, size_t ws_size,
                              hipStream_t stream) {
  (void)in_sizes; (void)n_in; (void)out_size; (void)ws_size;
  const int*   tokens      = (const int*)d_in[0];
  const float* E           = (const float*)d_in[1];
  const float* bases       = (const float*)d_in[2];
  const float* tension     = (const float*)d_in[3];
  const float* temperature = (const float*)d_in[4];
  const float* target      = (const float*)d_in[5];
  const float* stepsz      = (const float*)d_in[6];
  const float* alogit      = (const float*)d_in[7];
  const float* mdb         = (const float*)d_in[8];
  const float* sens        = (const float*)d_in[9];
  float* out = (float*)d_out;
  float* ws  = (float*)d_ws;

  foam_init<<<dim3(9, 4), 256, 0, stream>>>(bases, ws);
  foam_equil<<<3, 512, 0, stream>>>(tokens, E, tension, temperature, target,
                                    stepsz, alogit, mdb, sens, ws);
  foam_entropy<<<256, 64, 0, stream>>>(ws + WS_U, out);
  foam_logits<<<dim3(197, 8), 256, 0, stream>>>(E, ws + WS_U, out);
  foam_zh<<<256, 1024, 0, stream>>>(out, ws);
  foam_probs<<<dim3(197, 256), 256, 0, stream>>>(out, ws);
}